// Round 12
// baseline (983.681 us; speedup 1.0000x reference)
//
#include <hip/hip_runtime.h>
#include <hip/hip_bf16.h>

#define N_NODES 100000
#define N_EDGES 1600000
#define BKT_SHIFT 7                     // 128 nodes per bucket
#define BKT_NODES 128
#define NBKT ((N_NODES + BKT_NODES - 1) / BKT_NODES)   // 782

// ============================ CSR build ====================================
__global__ void hist_kernel(const int* __restrict__ dst, int* __restrict__ deg, int E) {
    int gid = blockIdx.x * blockDim.x + threadIdx.x;
    if (gid < E) atomicAdd(&deg[dst[gid]], 1);
}

__global__ void scan1(const int* __restrict__ deg, int* __restrict__ row_ptr,
                      int* __restrict__ partials, int N) {
    __shared__ int sh[1024];
    int gid = blockIdx.x * 1024 + threadIdx.x;
    int v = (gid < N) ? deg[gid] : 0;
    sh[threadIdx.x] = v;
    __syncthreads();
    for (int off = 1; off < 1024; off <<= 1) {
        int t = (threadIdx.x >= off) ? sh[threadIdx.x - off] : 0;
        __syncthreads();
        sh[threadIdx.x] += t;
        __syncthreads();
    }
    if (gid < N) row_ptr[gid] = sh[threadIdx.x] - v;  // exclusive
    if (threadIdx.x == 1023) partials[blockIdx.x] = sh[1023];
}

__global__ void scan2(int* __restrict__ partials, int nb) {
    __shared__ int sh[128];
    int v = (threadIdx.x < nb) ? partials[threadIdx.x] : 0;
    sh[threadIdx.x] = v;
    __syncthreads();
    for (int off = 1; off < 128; off <<= 1) {
        int t = (threadIdx.x >= off) ? sh[threadIdx.x - off] : 0;
        __syncthreads();
        sh[threadIdx.x] += t;
        __syncthreads();
    }
    if (threadIdx.x < nb) partials[threadIdx.x] = sh[threadIdx.x] - v;
}

__global__ void scan3(int* __restrict__ row_ptr, const int* __restrict__ partials,
                      int N, int E) {
    int gid = blockIdx.x * 1024 + threadIdx.x;
    if (gid < N) row_ptr[gid] += partials[blockIdx.x];
    if (gid == 0) row_ptr[N] = E;
}

// bucket cursors: bcur[b] = row_ptr[b*128]
__global__ void init_bcur(const int* __restrict__ row_ptr, int* __restrict__ bcur) {
    int b = threadIdx.x + blockIdx.x * blockDim.x;
    if (b < NBKT) bcur[b] = row_ptr[b * BKT_NODES];
}

// Phase 1: partition edges into 782 bucket regions (hot window = 782 cursor
// tails ~50KB -> L2 fills lines before eviction). Entry: ((dst&127)<<17)|src, w.
__global__ void place_bucket(const int* __restrict__ src, const int* __restrict__ dst,
                             const float* __restrict__ w, int* __restrict__ bcur,
                             int2* __restrict__ tmp, int E) {
    int gid = blockIdx.x * blockDim.x + threadIdx.x;
    if (gid < E) {
        int d = dst[gid];
        int b = d >> BKT_SHIFT;
        int pos = atomicAdd(&bcur[b], 1);
        tmp[pos] = make_int2(((d & (BKT_NODES - 1)) << 17) | src[gid],
                             __float_as_int(w[gid]));
    }
}

// Phase 2: one block per bucket; LDS per-node cursors; scatter within the
// bucket's contiguous ~16KB CSR region (L2-coalesced full lines).
__global__ __launch_bounds__(256) void place_local(const int2* __restrict__ tmp,
                                                   const int* __restrict__ row_ptr,
                                                   int2* __restrict__ csr) {
    __shared__ int lcur[BKT_NODES];
    int b = blockIdx.x;
    int node0 = b * BKT_NODES;
    if (threadIdx.x < BKT_NODES) {
        int node = node0 + threadIdx.x;
        lcur[threadIdx.x] = (node < N_NODES) ? row_ptr[node] : N_EDGES;
    }
    __syncthreads();
    int ebeg = row_ptr[node0];
    int nend = node0 + BKT_NODES; if (nend > N_NODES) nend = N_NODES;
    int eend = row_ptr[nend];
    for (int t = ebeg + threadIdx.x; t < eend; t += 256) {
        int2 e = tmp[t];
        int nl = e.x >> 17;
        int pos = atomicAdd(&lcur[nl], 1);
        csr[pos] = make_int2(e.x & 0x1FFFF, e.y);
    }
}

// ============================ GEMM layer 0 =================================
// P = X[N,128] @ W[128,64] + b.  4 rows x 16 cols per thread.
__global__ __launch_bounds__(256) void gemm0(const float* __restrict__ X,
                                             const float* __restrict__ W,
                                             const float* __restrict__ b,
                                             float* __restrict__ P, int N) {
    __shared__ float Ws[128 * 64];  // 32 KB
    for (int i = threadIdx.x; i < 128 * 64 / 4; i += blockDim.x)
        ((float4*)Ws)[i] = ((const float4*)W)[i];
    __syncthreads();

    int tid = blockIdx.x * blockDim.x + threadIdx.x;
    int cg = (tid & 3) * 16;
    int row0 = (tid >> 2) * 4;
    if (row0 >= N) return;

    float acc[4][16];
#pragma unroll
    for (int c = 0; c < 16; ++c) {
        float bc = b[cg + c];
#pragma unroll
        for (int r = 0; r < 4; ++r) acc[r][c] = bc;
    }

    for (int k0 = 0; k0 < 128; k0 += 4) {
        float4 xv[4];
#pragma unroll
        for (int r = 0; r < 4; ++r)
            xv[r] = *(const float4*)&X[(long)(row0 + r) * 128 + k0];
#pragma unroll
        for (int kk = 0; kk < 4; ++kk) {
            const float* wr = &Ws[(k0 + kk) * 64 + cg];
            float4 w0 = *(const float4*)&wr[0];
            float4 w1 = *(const float4*)&wr[4];
            float4 w2 = *(const float4*)&wr[8];
            float4 w3 = *(const float4*)&wr[12];
#pragma unroll
            for (int r = 0; r < 4; ++r) {
                float x = (&xv[r].x)[kk];
                acc[r][0]  = fmaf(x, w0.x, acc[r][0]);  acc[r][1]  = fmaf(x, w0.y, acc[r][1]);
                acc[r][2]  = fmaf(x, w0.z, acc[r][2]);  acc[r][3]  = fmaf(x, w0.w, acc[r][3]);
                acc[r][4]  = fmaf(x, w1.x, acc[r][4]);  acc[r][5]  = fmaf(x, w1.y, acc[r][5]);
                acc[r][6]  = fmaf(x, w1.z, acc[r][6]);  acc[r][7]  = fmaf(x, w1.w, acc[r][7]);
                acc[r][8]  = fmaf(x, w2.x, acc[r][8]);  acc[r][9]  = fmaf(x, w2.y, acc[r][9]);
                acc[r][10] = fmaf(x, w2.z, acc[r][10]); acc[r][11] = fmaf(x, w2.w, acc[r][11]);
                acc[r][12] = fmaf(x, w3.x, acc[r][12]); acc[r][13] = fmaf(x, w3.y, acc[r][13]);
                acc[r][14] = fmaf(x, w3.z, acc[r][14]); acc[r][15] = fmaf(x, w3.w, acc[r][15]);
            }
        }
    }
#pragma unroll
    for (int r = 0; r < 4; ++r)
#pragma unroll
        for (int c4 = 0; c4 < 4; ++c4)
            *(float4*)&P[(long)(row0 + r) * 64 + cg + c4 * 4] =
                make_float4(acc[r][c4 * 4], acc[r][c4 * 4 + 1], acc[r][c4 * 4 + 2], acc[r][c4 * 4 + 3]);
}

// ===================== Mid-layer GEMM (64->64, relu on input) ==============
template <int DIN, int DOUT, bool RELU>
__global__ void gemm4(const float* __restrict__ H, const float* __restrict__ W,
                      const float* __restrict__ b, float* __restrict__ out, int N) {
    __shared__ float Ws[DIN * DOUT];
    for (int i = threadIdx.x; i < DIN * DOUT / 4; i += blockDim.x)
        ((float4*)Ws)[i] = ((const float4*)W)[i];
    __syncthreads();

    int gid = blockIdx.x * blockDim.x + threadIdx.x;
    int row = gid / (DOUT / 4);
    int cg = (gid - row * (DOUT / 4)) * 4;
    if (row >= N) return;

    const float* h = H + (long)row * DIN;
    float4 acc = *(const float4*)&b[cg];
#pragma unroll
    for (int k0 = 0; k0 < DIN; k0 += 4) {
        float4 hv = *(const float4*)&h[k0];
        if (RELU) {
            hv.x = fmaxf(hv.x, 0.f); hv.y = fmaxf(hv.y, 0.f);
            hv.z = fmaxf(hv.z, 0.f); hv.w = fmaxf(hv.w, 0.f);
        }
#pragma unroll
        for (int kk = 0; kk < 4; ++kk) {
            float x = (&hv.x)[kk];
            float4 wv = *(const float4*)&Ws[(k0 + kk) * DOUT + cg];
            acc.x = fmaf(x, wv.x, acc.x); acc.y = fmaf(x, wv.y, acc.y);
            acc.z = fmaf(x, wv.z, acc.z); acc.w = fmaf(x, wv.w, acc.w);
        }
    }
    *(float4*)&out[(long)row * DOUT + cg] = acc;
}

// final projection 64->10 (relu on input), output stride 16 (64B rows)
__global__ void gemm_last(const float* __restrict__ H, const float* __restrict__ W,
                          const float* __restrict__ b, float* __restrict__ out, int N) {
    __shared__ float Ws[64 * 10];
    for (int i = threadIdx.x; i < 64 * 10; i += blockDim.x) Ws[i] = W[i];
    __syncthreads();
    int gid = blockIdx.x * blockDim.x + threadIdx.x;
    int row = gid / 10;
    int col = gid - row * 10;
    if (row >= N) return;
    const float* h = H + (long)row * 64;
    float acc = b[col];
#pragma unroll
    for (int k = 0; k < 64; ++k)
        acc = fmaf(fmaxf(h[k], 0.f), Ws[k * 10 + col], acc);
    out[(long)row * 16 + col] = acc;
}

// ======================== CSR aggregation ==================================
// Two nodes per wave: half = lane>>5 picks the node, 32 lanes x float2 cover
// the 64 features. 4-deep unroll -> ~8 independent gather loads in flight.
__global__ __launch_bounds__(256) void agg64v2(const float* __restrict__ P,
                                               const int2* __restrict__ csr,
                                               const int* __restrict__ row_ptr,
                                               float* __restrict__ A, int N) {
    int lane = threadIdx.x & 63;
    int half = lane >> 5;
    int fl = (lane & 31) * 2;
    long gw = ((long)blockIdx.x * blockDim.x + threadIdx.x) >> 6;
    int n = (int)(gw * 2) + half;
    if (n >= N) return;
    int beg = row_ptr[n], end = row_ptr[n + 1];

    float ax = 0.f, ay = 0.f;
    int j = beg;
    for (; j + 3 < end; j += 4) {
        int2 e0 = csr[j], e1 = csr[j + 1], e2 = csr[j + 2], e3 = csr[j + 3];
        float2 v0 = *(const float2*)&P[(size_t)((unsigned)e0.x * 64u + fl)];
        float2 v1 = *(const float2*)&P[(size_t)((unsigned)e1.x * 64u + fl)];
        float2 v2 = *(const float2*)&P[(size_t)((unsigned)e2.x * 64u + fl)];
        float2 v3 = *(const float2*)&P[(size_t)((unsigned)e3.x * 64u + fl)];
        float w0 = __int_as_float(e0.y), w1 = __int_as_float(e1.y);
        float w2 = __int_as_float(e2.y), w3 = __int_as_float(e3.y);
        ax = fmaf(w0, v0.x, ax); ay = fmaf(w0, v0.y, ay);
        ax = fmaf(w1, v1.x, ax); ay = fmaf(w1, v1.y, ay);
        ax = fmaf(w2, v2.x, ax); ay = fmaf(w2, v2.y, ay);
        ax = fmaf(w3, v3.x, ax); ay = fmaf(w3, v3.y, ay);
    }
    for (; j < end; ++j) {
        int2 e = csr[j];
        float2 v = *(const float2*)&P[(size_t)((unsigned)e.x * 64u + fl)];
        float w = __int_as_float(e.y);
        ax = fmaf(w, v.x, ax); ay = fmaf(w, v.y, ay);
    }
    *(float2*)&A[(size_t)n * 64 + fl] = make_float2(ax, ay);
}

// ===================== Final aggregation (width 10) ========================
__global__ __launch_bounds__(256) void agg10v2(const float* __restrict__ P,
                                               const int2* __restrict__ csr,
                                               const int* __restrict__ row_ptr,
                                               float* __restrict__ out, int N) {
    int lane = threadIdx.x & 63;
    int g  = lane >> 3;        // edge slot 0..7
    int sl = lane & 7;         // float2 slot, 0..4 active
    long gw = ((long)blockIdx.x * blockDim.x + threadIdx.x) >> 6;
    if (gw >= N) return;
    int n = (int)gw;
    int beg = row_ptr[n], end = row_ptr[n + 1];

    float ax = 0.f, ay = 0.f;
    for (int j0 = beg; j0 < end; j0 += 8) {
        int j = j0 + g;
        if (j < end && sl < 5) {
            int2 e = csr[j];
            float2 v = *(const float2*)&P[(size_t)((unsigned)e.x * 16u + sl * 2)];
            float w = __int_as_float(e.y);
            ax = fmaf(w, v.x, ax); ay = fmaf(w, v.y, ay);
        }
    }
#pragma unroll
    for (int m = 8; m <= 32; m <<= 1) {
        ax += __shfl_xor(ax, m);
        ay += __shfl_xor(ay, m);
    }
    if (g == 0 && sl < 5)
        *(float2*)&out[(size_t)n * 10 + sl * 2] = make_float2(ax, ay);
}

// ============================ driver =======================================
extern "C" void kernel_launch(void* const* d_in, const int* in_sizes, int n_in,
                              void* d_out, int out_size, void* d_ws, size_t ws_size,
                              hipStream_t stream) {
    const float* x        = (const float*)d_in[0];
    const int*   edge_src = (const int*)d_in[1];
    const int*   edge_dst = (const int*)d_in[2];
    const float* edge_w   = (const float*)d_in[3];
    const float* W0 = (const float*)d_in[4];   const float* b0 = (const float*)d_in[5];
    const float* W1 = (const float*)d_in[6];   const float* b1 = (const float*)d_in[7];
    const float* W2 = (const float*)d_in[8];   const float* b2 = (const float*)d_in[9];
    const float* W3 = (const float*)d_in[10];  const float* b3 = (const float*)d_in[11];
    const float* W4 = (const float*)d_in[12];  const float* b4 = (const float*)d_in[13];
    float* out = (float*)d_out;

    // ---- workspace layout (256B-aligned) ----
    char* p = (char*)d_ws;
    auto take = [&](size_t bytes) { char* r = p; p += (bytes + 255) & ~(size_t)255; return r; };
    float* B0       = (float*)take((size_t)N_NODES * 64 * sizeof(float));   // 25.6 MB
    float* B1f      = (float*)take((size_t)N_NODES * 64 * sizeof(float));   // 25.6 MB
    int2*  csr      = (int2*) take((size_t)N_EDGES * sizeof(int2));         // 12.8 MB
    int*   deg      = (int*)  take((size_t)N_NODES * sizeof(int));
    int*   row_ptr  = (int*)  take((size_t)(N_NODES + 1) * sizeof(int));
    int*   bcur     = (int*)  take((size_t)NBKT * sizeof(int));
    int*   partials = (int*)  take(1024 * sizeof(int));
    // bucket-tmp aliases B1f: dead until the first agg64v2 (CSR build precedes it)
    int2* tmp = (int2*)B1f;

    const int NB = (N_NODES + 1023) / 1024;
    const int EB = (N_EDGES + 255) / 256;

    // ---- CSR build (amortized over all 5 aggregations) ----
    hipMemsetAsync(deg, 0, (size_t)N_NODES * sizeof(int), stream);
    hist_kernel<<<EB, 256, 0, stream>>>(edge_dst, deg, N_EDGES);
    scan1<<<NB, 1024, 0, stream>>>(deg, row_ptr, partials, N_NODES);
    scan2<<<1, 128, 0, stream>>>(partials, NB);
    scan3<<<NB, 1024, 0, stream>>>(row_ptr, partials, N_NODES, N_EDGES);
    init_bcur<<<(NBKT + 255) / 256, 256, 0, stream>>>(row_ptr, bcur);
    place_bucket<<<EB, 256, 0, stream>>>(edge_src, edge_dst, edge_w, bcur, tmp, N_EDGES);
    place_local<<<NBKT, 256, 0, stream>>>(tmp, row_ptr, csr);

    // ---- Layer 0 projection: x @ W0 + b0 -> B0 ----
    gemm0<<<(N_NODES + 255) / 256, 256, 0, stream>>>(x, W0, b0, B0, N_NODES);

    // ---- agg/gemm ping-pong ----
    const int AGG2_BLOCKS = (((N_NODES + 1) / 2) * 64 + 255) / 256;  // 2 nodes/wave
    const int G4_BLOCKS = (N_NODES * 16 + 255) / 256;

    agg64v2<<<AGG2_BLOCKS, 256, 0, stream>>>(B0, csr, row_ptr, B1f, N_NODES);  // A0
    gemm4<64, 64, true><<<G4_BLOCKS, 256, 0, stream>>>(B1f, W1, b1, B0, N_NODES);  // P1
    agg64v2<<<AGG2_BLOCKS, 256, 0, stream>>>(B0, csr, row_ptr, B1f, N_NODES);  // A1
    gemm4<64, 64, true><<<G4_BLOCKS, 256, 0, stream>>>(B1f, W2, b2, B0, N_NODES);  // P2
    agg64v2<<<AGG2_BLOCKS, 256, 0, stream>>>(B0, csr, row_ptr, B1f, N_NODES);  // A2
    gemm4<64, 64, true><<<G4_BLOCKS, 256, 0, stream>>>(B1f, W3, b3, B0, N_NODES);  // P3
    agg64v2<<<AGG2_BLOCKS, 256, 0, stream>>>(B0, csr, row_ptr, B1f, N_NODES);  // A3

    // ---- Layer 4: project to 10 (stride 16) then aggregate ----
    gemm_last<<<(N_NODES * 10 + 255) / 256, 256, 0, stream>>>(B1f, W4, b4, B0, N_NODES);
    agg10v2<<<(N_NODES * 64 + 255) / 256, 256, 0, stream>>>(B0, csr, row_ptr, out, N_NODES);
}

// Round 14
// 699.008 us; speedup vs baseline: 1.4073x; 1.4073x over previous
//
#include <hip/hip_runtime.h>
#include <hip/hip_bf16.h>

#define N_NODES 100000
#define N_EDGES 1600000

// ============================ CSR build ====================================
__global__ void hist_kernel(const int* __restrict__ dst, int* __restrict__ deg, int E) {
    int gid = blockIdx.x * blockDim.x + threadIdx.x;
    if (gid < E) atomicAdd(&deg[dst[gid]], 1);
}

__global__ void scan1(const int* __restrict__ deg, int* __restrict__ row_ptr,
                      int* __restrict__ partials, int N) {
    __shared__ int sh[1024];
    int gid = blockIdx.x * 1024 + threadIdx.x;
    int v = (gid < N) ? deg[gid] : 0;
    sh[threadIdx.x] = v;
    __syncthreads();
    for (int off = 1; off < 1024; off <<= 1) {
        int t = (threadIdx.x >= off) ? sh[threadIdx.x - off] : 0;
        __syncthreads();
        sh[threadIdx.x] += t;
        __syncthreads();
    }
    if (gid < N) row_ptr[gid] = sh[threadIdx.x] - v;  // exclusive
    if (threadIdx.x == 1023) partials[blockIdx.x] = sh[1023];
}

__global__ void scan2(int* __restrict__ partials, int nb) {
    __shared__ int sh[128];
    int v = (threadIdx.x < nb) ? partials[threadIdx.x] : 0;
    sh[threadIdx.x] = v;
    __syncthreads();
    for (int off = 1; off < 128; off <<= 1) {
        int t = (threadIdx.x >= off) ? sh[threadIdx.x - off] : 0;
        __syncthreads();
        sh[threadIdx.x] += t;
        __syncthreads();
    }
    if (threadIdx.x < nb) partials[threadIdx.x] = sh[threadIdx.x] - v;
}

__global__ void scan3(int* __restrict__ row_ptr, int* __restrict__ cursor,
                      const int* __restrict__ partials, int N, int E) {
    int gid = blockIdx.x * 1024 + threadIdx.x;
    if (gid < N) {
        int r = row_ptr[gid] + partials[blockIdx.x];
        row_ptr[gid] = r;
        cursor[gid] = r;
    }
    if (gid == 0) row_ptr[N] = E;
}

// Packed placement: one 8B store per edge; 100K cursors -> ~16 atomics/address
// (per-address far-atomic serialization ~180ns/op: needs >=10K counters).
__global__ void place_kernel(const int* __restrict__ src, const int* __restrict__ dst,
                             const float* __restrict__ w, int* __restrict__ cursor,
                             int2* __restrict__ csr, int E) {
    int gid = blockIdx.x * blockDim.x + threadIdx.x;
    if (gid < E) {
        int d = dst[gid];
        int pos = atomicAdd(&cursor[d], 1);
        csr[pos] = make_int2(src[gid], __float_as_int(w[gid]));
    }
}

// ============================ GEMM layer 0 =================================
// P = X[N,128] @ W[128,64] + b.  4 rows x 16 cols per thread.
__global__ __launch_bounds__(256) void gemm0(const float* __restrict__ X,
                                             const float* __restrict__ W,
                                             const float* __restrict__ b,
                                             float* __restrict__ P, int N) {
    __shared__ float Ws[128 * 64];  // 32 KB
    for (int i = threadIdx.x; i < 128 * 64 / 4; i += blockDim.x)
        ((float4*)Ws)[i] = ((const float4*)W)[i];
    __syncthreads();

    int tid = blockIdx.x * blockDim.x + threadIdx.x;
    int cg = (tid & 3) * 16;
    int row0 = (tid >> 2) * 4;
    if (row0 >= N) return;

    float acc[4][16];
#pragma unroll
    for (int c = 0; c < 16; ++c) {
        float bc = b[cg + c];
#pragma unroll
        for (int r = 0; r < 4; ++r) acc[r][c] = bc;
    }

    for (int k0 = 0; k0 < 128; k0 += 4) {
        float4 xv[4];
#pragma unroll
        for (int r = 0; r < 4; ++r)
            xv[r] = *(const float4*)&X[(long)(row0 + r) * 128 + k0];
#pragma unroll
        for (int kk = 0; kk < 4; ++kk) {
            const float* wr = &Ws[(k0 + kk) * 64 + cg];
            float4 w0 = *(const float4*)&wr[0];
            float4 w1 = *(const float4*)&wr[4];
            float4 w2 = *(const float4*)&wr[8];
            float4 w3 = *(const float4*)&wr[12];
#pragma unroll
            for (int r = 0; r < 4; ++r) {
                float x = (&xv[r].x)[kk];
                acc[r][0]  = fmaf(x, w0.x, acc[r][0]);  acc[r][1]  = fmaf(x, w0.y, acc[r][1]);
                acc[r][2]  = fmaf(x, w0.z, acc[r][2]);  acc[r][3]  = fmaf(x, w0.w, acc[r][3]);
                acc[r][4]  = fmaf(x, w1.x, acc[r][4]);  acc[r][5]  = fmaf(x, w1.y, acc[r][5]);
                acc[r][6]  = fmaf(x, w1.z, acc[r][6]);  acc[r][7]  = fmaf(x, w1.w, acc[r][7]);
                acc[r][8]  = fmaf(x, w2.x, acc[r][8]);  acc[r][9]  = fmaf(x, w2.y, acc[r][9]);
                acc[r][10] = fmaf(x, w2.z, acc[r][10]); acc[r][11] = fmaf(x, w2.w, acc[r][11]);
                acc[r][12] = fmaf(x, w3.x, acc[r][12]); acc[r][13] = fmaf(x, w3.y, acc[r][13]);
                acc[r][14] = fmaf(x, w3.z, acc[r][14]); acc[r][15] = fmaf(x, w3.w, acc[r][15]);
            }
        }
    }
#pragma unroll
    for (int r = 0; r < 4; ++r)
#pragma unroll
        for (int c4 = 0; c4 < 4; ++c4)
            *(float4*)&P[(long)(row0 + r) * 64 + cg + c4 * 4] =
                make_float4(acc[r][c4 * 4], acc[r][c4 * 4 + 1], acc[r][c4 * 4 + 2], acc[r][c4 * 4 + 3]);
}

// ===================== Mid-layer GEMM (64->64, relu on input) ==============
template <int DIN, int DOUT, bool RELU>
__global__ void gemm4(const float* __restrict__ H, const float* __restrict__ W,
                      const float* __restrict__ b, float* __restrict__ out, int N) {
    __shared__ float Ws[DIN * DOUT];
    for (int i = threadIdx.x; i < DIN * DOUT / 4; i += blockDim.x)
        ((float4*)Ws)[i] = ((const float4*)W)[i];
    __syncthreads();

    int gid = blockIdx.x * blockDim.x + threadIdx.x;
    int row = gid / (DOUT / 4);
    int cg = (gid - row * (DOUT / 4)) * 4;
    if (row >= N) return;

    const float* h = H + (long)row * DIN;
    float4 acc = *(const float4*)&b[cg];
#pragma unroll
    for (int k0 = 0; k0 < DIN; k0 += 4) {
        float4 hv = *(const float4*)&h[k0];
        if (RELU) {
            hv.x = fmaxf(hv.x, 0.f); hv.y = fmaxf(hv.y, 0.f);
            hv.z = fmaxf(hv.z, 0.f); hv.w = fmaxf(hv.w, 0.f);
        }
#pragma unroll
        for (int kk = 0; kk < 4; ++kk) {
            float x = (&hv.x)[kk];
            float4 wv = *(const float4*)&Ws[(k0 + kk) * DOUT + cg];
            acc.x = fmaf(x, wv.x, acc.x); acc.y = fmaf(x, wv.y, acc.y);
            acc.z = fmaf(x, wv.z, acc.z); acc.w = fmaf(x, wv.w, acc.w);
        }
    }
    *(float4*)&out[(long)row * DOUT + cg] = acc;
}

// final projection 64->10 (relu on input), output stride 16 (64B rows)
__global__ void gemm_last(const float* __restrict__ H, const float* __restrict__ W,
                          const float* __restrict__ b, float* __restrict__ out, int N) {
    __shared__ float Ws[64 * 10];
    for (int i = threadIdx.x; i < 64 * 10; i += blockDim.x) Ws[i] = W[i];
    __syncthreads();
    int gid = blockIdx.x * blockDim.x + threadIdx.x;
    int row = gid / 10;
    int col = gid - row * 10;
    if (row >= N) return;
    const float* h = H + (long)row * 64;
    float acc = b[col];
#pragma unroll
    for (int k = 0; k < 64; ++k)
        acc = fmaf(fmaxf(h[k], 0.f), Ws[k * 10 + col], acc);
    out[(long)row * 16 + col] = acc;
}

// ======================== CSR aggregation ==================================
// Two nodes per wave, 32 lanes x float2 each; 8-deep unroll -> ~16 independent
// gather loads in flight per wave (latency-bound gather: MLP is the lever).
__global__ __launch_bounds__(256) void agg64v2(const float* __restrict__ P,
                                               const int2* __restrict__ csr,
                                               const int* __restrict__ row_ptr,
                                               float* __restrict__ A, int N) {
    int lane = threadIdx.x & 63;
    int half = lane >> 5;
    int fl = (lane & 31) * 2;
    long gw = ((long)blockIdx.x * blockDim.x + threadIdx.x) >> 6;
    int n = (int)(gw * 2) + half;
    if (n >= N) return;
    int beg = row_ptr[n], end = row_ptr[n + 1];

    float ax = 0.f, ay = 0.f;
    int j = beg;
    for (; j + 7 < end; j += 8) {
        int2 e0 = csr[j],     e1 = csr[j + 1], e2 = csr[j + 2], e3 = csr[j + 3];
        int2 e4 = csr[j + 4], e5 = csr[j + 5], e6 = csr[j + 6], e7 = csr[j + 7];
        float2 v0 = *(const float2*)&P[(size_t)((unsigned)e0.x * 64u + fl)];
        float2 v1 = *(const float2*)&P[(size_t)((unsigned)e1.x * 64u + fl)];
        float2 v2 = *(const float2*)&P[(size_t)((unsigned)e2.x * 64u + fl)];
        float2 v3 = *(const float2*)&P[(size_t)((unsigned)e3.x * 64u + fl)];
        float2 v4 = *(const float2*)&P[(size_t)((unsigned)e4.x * 64u + fl)];
        float2 v5 = *(const float2*)&P[(size_t)((unsigned)e5.x * 64u + fl)];
        float2 v6 = *(const float2*)&P[(size_t)((unsigned)e6.x * 64u + fl)];
        float2 v7 = *(const float2*)&P[(size_t)((unsigned)e7.x * 64u + fl)];
        float w0 = __int_as_float(e0.y), w1 = __int_as_float(e1.y);
        float w2 = __int_as_float(e2.y), w3 = __int_as_float(e3.y);
        float w4 = __int_as_float(e4.y), w5 = __int_as_float(e5.y);
        float w6 = __int_as_float(e6.y), w7 = __int_as_float(e7.y);
        ax = fmaf(w0, v0.x, ax); ay = fmaf(w0, v0.y, ay);
        ax = fmaf(w1, v1.x, ax); ay = fmaf(w1, v1.y, ay);
        ax = fmaf(w2, v2.x, ax); ay = fmaf(w2, v2.y, ay);
        ax = fmaf(w3, v3.x, ax); ay = fmaf(w3, v3.y, ay);
        ax = fmaf(w4, v4.x, ax); ay = fmaf(w4, v4.y, ay);
        ax = fmaf(w5, v5.x, ax); ay = fmaf(w5, v5.y, ay);
        ax = fmaf(w6, v6.x, ax); ay = fmaf(w6, v6.y, ay);
        ax = fmaf(w7, v7.x, ax); ay = fmaf(w7, v7.y, ay);
    }
    for (; j + 3 < end; j += 4) {
        int2 e0 = csr[j], e1 = csr[j + 1], e2 = csr[j + 2], e3 = csr[j + 3];
        float2 v0 = *(const float2*)&P[(size_t)((unsigned)e0.x * 64u + fl)];
        float2 v1 = *(const float2*)&P[(size_t)((unsigned)e1.x * 64u + fl)];
        float2 v2 = *(const float2*)&P[(size_t)((unsigned)e2.x * 64u + fl)];
        float2 v3 = *(const float2*)&P[(size_t)((unsigned)e3.x * 64u + fl)];
        float w0 = __int_as_float(e0.y), w1 = __int_as_float(e1.y);
        float w2 = __int_as_float(e2.y), w3 = __int_as_float(e3.y);
        ax = fmaf(w0, v0.x, ax); ay = fmaf(w0, v0.y, ay);
        ax = fmaf(w1, v1.x, ax); ay = fmaf(w1, v1.y, ay);
        ax = fmaf(w2, v2.x, ax); ay = fmaf(w2, v2.y, ay);
        ax = fmaf(w3, v3.x, ax); ay = fmaf(w3, v3.y, ay);
    }
    for (; j < end; ++j) {
        int2 e = csr[j];
        float2 v = *(const float2*)&P[(size_t)((unsigned)e.x * 64u + fl)];
        float w = __int_as_float(e.y);
        ax = fmaf(w, v.x, ax); ay = fmaf(w, v.y, ay);
    }
    *(float2*)&A[(size_t)n * 64 + fl] = make_float2(ax, ay);
}

// ===================== Final aggregation (width 10) ========================
__global__ __launch_bounds__(256) void agg10v2(const float* __restrict__ P,
                                               const int2* __restrict__ csr,
                                               const int* __restrict__ row_ptr,
                                               float* __restrict__ out, int N) {
    int lane = threadIdx.x & 63;
    int g  = lane >> 3;        // edge slot 0..7
    int sl = lane & 7;         // float2 slot, 0..4 active
    long gw = ((long)blockIdx.x * blockDim.x + threadIdx.x) >> 6;
    if (gw >= N) return;
    int n = (int)gw;
    int beg = row_ptr[n], end = row_ptr[n + 1];

    float ax = 0.f, ay = 0.f;
    for (int j0 = beg; j0 < end; j0 += 8) {
        int j = j0 + g;
        if (j < end && sl < 5) {
            int2 e = csr[j];
            float2 v = *(const float2*)&P[(size_t)((unsigned)e.x * 16u + sl * 2)];
            float w = __int_as_float(e.y);
            ax = fmaf(w, v.x, ax); ay = fmaf(w, v.y, ay);
        }
    }
#pragma unroll
    for (int m = 8; m <= 32; m <<= 1) {
        ax += __shfl_xor(ax, m);
        ay += __shfl_xor(ay, m);
    }
    if (g == 0 && sl < 5)
        *(float2*)&out[(size_t)n * 10 + sl * 2] = make_float2(ax, ay);
}

// ============================ driver =======================================
extern "C" void kernel_launch(void* const* d_in, const int* in_sizes, int n_in,
                              void* d_out, int out_size, void* d_ws, size_t ws_size,
                              hipStream_t stream) {
    const float* x        = (const float*)d_in[0];
    const int*   edge_src = (const int*)d_in[1];
    const int*   edge_dst = (const int*)d_in[2];
    const float* edge_w   = (const float*)d_in[3];
    const float* W0 = (const float*)d_in[4];   const float* b0 = (const float*)d_in[5];
    const float* W1 = (const float*)d_in[6];   const float* b1 = (const float*)d_in[7];
    const float* W2 = (const float*)d_in[8];   const float* b2 = (const float*)d_in[9];
    const float* W3 = (const float*)d_in[10];  const float* b3 = (const float*)d_in[11];
    const float* W4 = (const float*)d_in[12];  const float* b4 = (const float*)d_in[13];
    float* out = (float*)d_out;

    // ---- workspace layout (256B-aligned) ----
    char* p = (char*)d_ws;
    auto take = [&](size_t bytes) { char* r = p; p += (bytes + 255) & ~(size_t)255; return r; };
    float* B0       = (float*)take((size_t)N_NODES * 64 * sizeof(float));   // 25.6 MB
    float* B1f      = (float*)take((size_t)N_NODES * 64 * sizeof(float));   // 25.6 MB
    int2*  csr      = (int2*) take((size_t)N_EDGES * sizeof(int2));         // 12.8 MB
    int*   deg      = (int*)  take((size_t)N_NODES * sizeof(int));
    int*   row_ptr  = (int*)  take((size_t)(N_NODES + 1) * sizeof(int));
    int*   cursor   = (int*)  take((size_t)N_NODES * sizeof(int));
    int*   partials = (int*)  take(1024 * sizeof(int));

    const int NB = (N_NODES + 1023) / 1024;
    const int EB = (N_EDGES + 255) / 256;

    // ---- CSR build (amortized over all 5 aggregations) ----
    hipMemsetAsync(deg, 0, (size_t)N_NODES * sizeof(int), stream);
    hist_kernel<<<EB, 256, 0, stream>>>(edge_dst, deg, N_EDGES);
    scan1<<<NB, 1024, 0, stream>>>(deg, row_ptr, partials, N_NODES);
    scan2<<<1, 128, 0, stream>>>(partials, NB);
    scan3<<<NB, 1024, 0, stream>>>(row_ptr, cursor, partials, N_NODES, N_EDGES);
    place_kernel<<<EB, 256, 0, stream>>>(edge_src, edge_dst, edge_w, cursor, csr, N_EDGES);

    // ---- Layer 0 projection: x @ W0 + b0 -> B0 ----
    gemm0<<<(N_NODES + 255) / 256, 256, 0, stream>>>(x, W0, b0, B0, N_NODES);

    // ---- agg/gemm ping-pong ----
    const int AGG2_BLOCKS = (((N_NODES + 1) / 2) * 64 + 255) / 256;  // 2 nodes/wave
    const int G4_BLOCKS = (N_NODES * 16 + 255) / 256;

    agg64v2<<<AGG2_BLOCKS, 256, 0, stream>>>(B0, csr, row_ptr, B1f, N_NODES);  // A0
    gemm4<64, 64, true><<<G4_BLOCKS, 256, 0, stream>>>(B1f, W1, b1, B0, N_NODES);  // P1
    agg64v2<<<AGG2_BLOCKS, 256, 0, stream>>>(B0, csr, row_ptr, B1f, N_NODES);  // A1
    gemm4<64, 64, true><<<G4_BLOCKS, 256, 0, stream>>>(B1f, W2, b2, B0, N_NODES);  // P2
    agg64v2<<<AGG2_BLOCKS, 256, 0, stream>>>(B0, csr, row_ptr, B1f, N_NODES);  // A2
    gemm4<64, 64, true><<<G4_BLOCKS, 256, 0, stream>>>(B1f, W3, b3, B0, N_NODES);  // P3
    agg64v2<<<AGG2_BLOCKS, 256, 0, stream>>>(B0, csr, row_ptr, B1f, N_NODES);  // A3

    // ---- Layer 4: project to 10 (stride 16) then aggregate ----
    gemm_last<<<(N_NODES * 10 + 255) / 256, 256, 0, stream>>>(B1f, W4, b4, B0, N_NODES);
    agg10v2<<<(N_NODES * 64 + 255) / 256, 256, 0, stream>>>(B0, csr, row_ptr, out, N_NODES);
}